// Round 1
// 21160.620 us; speedup vs baseline: 1.6182x; 1.6182x over previous
//
#include <hip/hip_runtime.h>
#include <math.h>

#define DD    1024
#define BB    128
#define G3    3072
#define VOUT  8000
#define S_SRC 256
#define S_TGT 128
#define SOS   1
#define KS    4          // split-K for recurrent gate GEMMs
#define KSL   2          // split-K for logits GEMM

// ---------------------------------------------------------------------------
// init: h = 0, tok = SOS
// ---------------------------------------------------------------------------
__global__ __launch_bounds__(256) void k_init(float* __restrict__ h, int* __restrict__ tok) {
    int idx = blockIdx.x * 256 + threadIdx.x;
    if (idx < BB * DD) h[idx] = 0.0f;
    if (idx < BB) tok[idx] = SOS;
}

// ---------------------------------------------------------------------------
// Shared GEMM core: BM=128, BN=32, BK=32 tile, 256 threads, 8x2 micro-tile.
// A rows given as 4 per-thread row pointers (rows r0, r0+32, r0+64, r0+96).
// Computes acc += A[:, kbeg:kbeg+ntiles*32] * B^T slice.
// strides 132 / 36 keep LDS rows 16B-aligned.
// ---------------------------------------------------------------------------
__device__ __forceinline__ void gemm_core(
    const float* __restrict__ A0, const float* __restrict__ A1,
    const float* __restrict__ A2, const float* __restrict__ A3,
    const float* __restrict__ Brow, int kbeg, int ntiles,
    float (&acc)[8][2])
{
    __shared__ float As[32][132];   // [k][m]
    __shared__ float Bs[32][36];    // [k][n]
    const int tid = threadIdx.x;
    const int kq  = (tid & 7) * 4;   // k quad within tile
    const int r0  = tid >> 3;        // 0..31
    const int tx  = tid & 15, ty = tid >> 4;
    const float* Arow[4] = {A0, A1, A2, A3};

    for (int t = 0; t < ntiles; ++t) {
        const int k0 = kbeg + t * 32;
        #pragma unroll
        for (int p = 0; p < 4; ++p) {
            float4 v = *reinterpret_cast<const float4*>(Arow[p] + k0 + kq);
            int m = r0 + p * 32;
            As[kq+0][m] = v.x; As[kq+1][m] = v.y; As[kq+2][m] = v.z; As[kq+3][m] = v.w;
        }
        {
            float4 v = *reinterpret_cast<const float4*>(Brow + k0 + kq);
            Bs[kq+0][r0] = v.x; Bs[kq+1][r0] = v.y; Bs[kq+2][r0] = v.z; Bs[kq+3][r0] = v.w;
        }
        __syncthreads();
        #pragma unroll
        for (int k = 0; k < 32; ++k) {
            float a[8];
            #pragma unroll
            for (int i = 0; i < 8; ++i) a[i] = As[k][ty*8 + i];
            float b0 = Bs[k][tx*2 + 0], b1 = Bs[k][tx*2 + 1];
            #pragma unroll
            for (int i = 0; i < 8; ++i) {
                acc[i][0] = fmaf(a[i], b0, acc[i][0]);
                acc[i][1] = fmaf(a[i], b1, acc[i][1]);
            }
        }
        __syncthreads();
    }
}

// ---------------------------------------------------------------------------
// Chunked encoder input projection: gi_buf[m, n] = emb[src_c[m]] . Wih[n] + bih[n]
// for m in [0, CH*128). grid = (96, CH). Full K. High occupancy (3 blocks/CU).
// ---------------------------------------------------------------------------
__global__ __launch_bounds__(256) void k_gi_chunk(
    const float* __restrict__ emb, const int* __restrict__ src_c,
    const float* __restrict__ Wih, const float* __restrict__ bih,
    float* __restrict__ gi_buf)
{
    const int n0    = blockIdx.x * 32;
    const int mbase = blockIdx.y * 128;
    const int tid = threadIdx.x;
    const int r0  = tid >> 3;
    const int tx  = tid & 15, ty = tid >> 4;

    const float* A[4];
    #pragma unroll
    for (int p = 0; p < 4; ++p)
        A[p] = emb + (size_t)src_c[mbase + r0 + p * 32] * DD;
    const float* Brow = Wih + (size_t)(n0 + r0) * DD;

    float acc[8][2] = {};
    gemm_core(A[0], A[1], A[2], A[3], Brow, 0, DD / 32, acc);

    #pragma unroll
    for (int i = 0; i < 8; ++i) {
        size_t m = (size_t)(mbase + ty*8 + i);
        #pragma unroll
        for (int j = 0; j < 2; ++j) {
            int n = n0 + tx*2 + j;
            gi_buf[m * G3 + n] = acc[i][j] + bih[n];
        }
    }
}

// ---------------------------------------------------------------------------
// Split-K gate GEMMs (raw partials, no bias):
//   side = side_base + blockIdx.y  (0: gi from emb[tok], 1: gh from h)
//   kh   = blockIdx.z  in [0, KS)
//   partial kh of side s goes to (s ? gh_base : gi_base) + kh*BB*G3
// Encoder gh-only: grid (96, 1, KS), side_base = 1.
// Decoder both:    grid (96, 2, KS), side_base = 0.
// ---------------------------------------------------------------------------
__global__ __launch_bounds__(256) void k_gates_ks(
    const float* __restrict__ emb, const int* __restrict__ tok,
    const float* __restrict__ h,
    const float* __restrict__ Wih, const float* __restrict__ Whh,
    float* __restrict__ gi_base, float* __restrict__ gh_base,
    int side_base)
{
    const int side = side_base + blockIdx.y;
    const int kh   = blockIdx.z;
    const int kseg = DD / KS;
    const float* __restrict__ W = side ? Whh : Wih;
    float* __restrict__ C = (side ? gh_base : gi_base) + (size_t)kh * (BB * G3);

    const int n0  = blockIdx.x * 32;
    const int tid = threadIdx.x;
    const int r0  = tid >> 3;
    const int tx  = tid & 15, ty = tid >> 4;

    const float* A[4];
    #pragma unroll
    for (int p = 0; p < 4; ++p) {
        int m = r0 + p * 32;
        A[p] = side ? (h + (size_t)m * DD)
                    : (emb + (size_t)tok[m] * DD);
    }
    const float* Brow = W + (size_t)(n0 + r0) * DD;

    float acc[8][2] = {};
    gemm_core(A[0], A[1], A[2], A[3], Brow, kh * kseg, kseg / 32, acc);

    #pragma unroll
    for (int i = 0; i < 8; ++i) {
        size_t m = (size_t)(ty*8 + i);
        C[m * G3 + n0 + tx*2 + 0] = acc[i][0];
        C[m * G3 + n0 + tx*2 + 1] = acc[i][1];
    }
}

// ---------------------------------------------------------------------------
// Split-K logits GEMM (raw partials): grid (250, KSL); partial kh at
// p_base + kh*BB*VOUT.
// ---------------------------------------------------------------------------
__global__ __launch_bounds__(256) void k_logits_ks(
    const float* __restrict__ h, const float* __restrict__ W,
    float* __restrict__ p_base)
{
    const int kh   = blockIdx.y;
    const int kseg = DD / KSL;
    float* __restrict__ C = p_base + (size_t)kh * (BB * VOUT);

    const int n0  = blockIdx.x * 32;
    const int tid = threadIdx.x;
    const int r0  = tid >> 3;
    const int tx  = tid & 15, ty = tid >> 4;

    const float* A[4];
    #pragma unroll
    for (int p = 0; p < 4; ++p) A[p] = h + (size_t)(r0 + p * 32) * DD;
    const float* Brow = W + (size_t)(n0 + r0) * DD;

    float acc[8][2] = {};
    gemm_core(A[0], A[1], A[2], A[3], Brow, kh * kseg, kseg / 32, acc);

    #pragma unroll
    for (int i = 0; i < 8; ++i) {
        size_t m = (size_t)(ty*8 + i);
        C[m * VOUT + n0 + tx*2 + 0] = acc[i][0];
        C[m * VOUT + n0 + tx*2 + 1] = acc[i][1];
    }
}

// ---------------------------------------------------------------------------
// GRU elementwise update, summing split-K partials + biases:
//   gi = sum_{p<ns_i} gi_base[p] (+ bih if non-null; encoder gi is pre-biased)
//   gh = sum_{p<ns_h} gh_base[p] + bhh
//   h  = (1-z)*n + z*h
// ---------------------------------------------------------------------------
__global__ __launch_bounds__(256) void k_update(
    const float* __restrict__ gi_base, int ns_i, const float* __restrict__ bih,
    const float* __restrict__ gh_base, int ns_h, const float* __restrict__ bhh,
    float* __restrict__ h)
{
    int idx = blockIdx.x * 256 + threadIdx.x;   // 0 .. 128*1024-1
    int b = idx >> 10, d = idx & 1023;
    size_t o = (size_t)b * G3 + d;

    float ir = 0.f, iz = 0.f, in_ = 0.f;
    for (int p = 0; p < ns_i; ++p) {
        const float* g = gi_base + (size_t)p * (BB * G3);
        ir += g[o]; iz += g[o + DD]; in_ += g[o + 2*DD];
    }
    if (bih) { ir += bih[d]; iz += bih[DD + d]; in_ += bih[2*DD + d]; }

    float hr = 0.f, hz = 0.f, hn = 0.f;
    for (int p = 0; p < ns_h; ++p) {
        const float* g = gh_base + (size_t)p * (BB * G3);
        hr += g[o]; hz += g[o + DD]; hn += g[o + 2*DD];
    }
    hr += bhh[d]; hz += bhh[DD + d]; hn += bhh[2*DD + d];

    float r = 1.0f / (1.0f + expf(-(ir + hr)));
    float z = 1.0f / (1.0f + expf(-(iz + hz)));
    float n = tanhf(in_ + r * hn);
    float hv = h[idx];
    h[idx] = (1.0f - z) * n + z * hv;
}

// ---------------------------------------------------------------------------
// Fused: logits = p0 + p1 + bias  -> store to out row, argmax -> tok.
// First-occurrence tie-break (matches jnp.argmax).
// ---------------------------------------------------------------------------
__global__ __launch_bounds__(256) void k_argmax_out(
    const float* __restrict__ p0, const float* __restrict__ p1,
    const float* __restrict__ bias,
    float* __restrict__ outC, int* __restrict__ tok)
{
    const int b = blockIdx.x;
    const size_t ro = (size_t)b * VOUT;
    const int tid = threadIdx.x;

    float bv = -INFINITY; int bi = 0x7fffffff;
    for (int v = tid * 4; v < VOUT; v += 1024) {
        float4 a = *reinterpret_cast<const float4*>(p0 + ro + v);
        float4 c = *reinterpret_cast<const float4*>(p1 + ro + v);
        float4 bb = *reinterpret_cast<const float4*>(bias + v);
        float4 r;
        r.x = a.x + c.x + bb.x;
        r.y = a.y + c.y + bb.y;
        r.z = a.z + c.z + bb.z;
        r.w = a.w + c.w + bb.w;
        *reinterpret_cast<float4*>(outC + ro + v) = r;
        if (r.x > bv) { bv = r.x; bi = v + 0; }
        if (r.y > bv) { bv = r.y; bi = v + 1; }
        if (r.z > bv) { bv = r.z; bi = v + 2; }
        if (r.w > bv) { bv = r.w; bi = v + 3; }
    }
    __shared__ float sv[256];
    __shared__ int   si[256];
    sv[tid] = bv; si[tid] = bi;
    __syncthreads();
    for (int s = 128; s > 0; s >>= 1) {
        if (tid < s) {
            if (sv[tid+s] > sv[tid] || (sv[tid+s] == sv[tid] && si[tid+s] < si[tid])) {
                sv[tid] = sv[tid+s]; si[tid] = si[tid+s];
            }
        }
        __syncthreads();
    }
    if (tid == 0) tok[b] = si[0];
}

// ---------------------------------------------------------------------------
extern "C" void kernel_launch(void* const* d_in, const int* in_sizes, int n_in,
                              void* d_out, int out_size, void* d_ws, size_t ws_size,
                              hipStream_t stream) {
    const int*   src     = (const int*)  d_in[0];
    // d_in[1] = tgt (only its length 128 matters, hard-coded)
    const float* enc_emb = (const float*)d_in[2];
    const float* eWih    = (const float*)d_in[3];
    const float* eWhh    = (const float*)d_in[4];
    const float* ebih    = (const float*)d_in[5];
    const float* ebhh    = (const float*)d_in[6];
    const float* dec_emb = (const float*)d_in[7];
    const float* dWih    = (const float*)d_in[8];
    const float* dWhh    = (const float*)d_in[9];
    const float* dbih    = (const float*)d_in[10];
    const float* dbhh    = (const float*)d_in[11];
    const float* outW    = (const float*)d_in[12];
    const float* outb    = (const float*)d_in[13];
    float* out = (float*)d_out;

    // workspace layout
    float* h    = (float*)d_ws;                 // 128*1024
    float* gi_p = h + BB * DD;                  // KS * 128*3072 (decoder gi partials)
    float* gh_p = gi_p + KS * BB * G3;          // KS * 128*3072 (gh partials)
    int*  tok   = (int*)(gh_p + KS * BB * G3);  // 128 (padded to 256)
    float* scratch = (float*)(tok + 256);       // encoder gi chunks / logits partials

    // chunk size for encoder input-projection hoist; overlaid with logits partials
    size_t fixed_bytes = (size_t)((char*)scratch - (char*)d_ws);
    int CH = 8;
    while (CH > 1) {
        size_t scr = (size_t)CH * BB * G3;
        size_t scr2 = (size_t)KSL * BB * VOUT;
        if (scr < scr2) scr = scr2;
        if (fixed_bytes + scr * sizeof(float) <= ws_size) break;
        CH >>= 1;
    }
    float* gi_buf = scratch;                    // encoder phase
    float* p0     = scratch;                    // decoder phase
    float* p1     = scratch + BB * VOUT;

    k_init<<<512, 256, 0, stream>>>(h, tok);

    // ---- Encoder: hoisted input projection (chunked) + split-K recurrent gh ----
    for (int c = 0; c < S_SRC; c += CH) {
        k_gi_chunk<<<dim3(96, CH), 256, 0, stream>>>(enc_emb, src + c * BB,
                                                     eWih, ebih, gi_buf);
        for (int s = 0; s < CH; ++s) {
            k_gates_ks<<<dim3(96, 1, KS), 256, 0, stream>>>(enc_emb, tok, h,
                                                            eWih, eWhh,
                                                            nullptr, gh_p, 1);
            k_update<<<512, 256, 0, stream>>>(gi_buf + (size_t)s * BB * G3, 1, nullptr,
                                              gh_p, KS, ebhh, h);
        }
    }

    // ---- Decoder: split-K gates + update + split-K logits + fused argmax ----
    for (int t = 0; t < S_TGT; ++t) {
        k_gates_ks<<<dim3(96, 2, KS), 256, 0, stream>>>(dec_emb, tok, h,
                                                        dWih, dWhh,
                                                        gi_p, gh_p, 0);
        k_update<<<512, 256, 0, stream>>>(gi_p, KS, dbih, gh_p, KS, dbhh, h);
        k_logits_ks<<<dim3(250, KSL), 256, 0, stream>>>(h, outW, p0);
        float* Ct = out + (size_t)t * BB * VOUT;
        k_argmax_out<<<128, 256, 0, stream>>>(p0, p1, outb, Ct, tok);
    }
}